// Round 1
// 580.036 us; speedup vs baseline: 7.0431x; 7.0431x over previous
//
#include <hip/hip_runtime.h>
#include <stdint.h>
#include <stddef.h>

#define A_N 384
#define F_N 128
#define C_N 32
#define H_N 512
#define LN_EPS 1e-5f

typedef unsigned short u16;
typedef _Float16 f16;
typedef f16 f16x8 __attribute__((ext_vector_type(8)));
typedef float f32x4 __attribute__((ext_vector_type(4)));

// ---- scratch in static device memory (d_ws unused) ----
__device__ float g_left[A_N * C_N];
__device__ float g_right[A_N * C_N];
__device__ float g_M[A_N * F_N * C_N];      // [b][f][c] fp32
__device__ f16   gW1T[H_N * F_N];           // [h][k]  = w_t1[k][h]   (fp16)
__device__ f16   gW2T[F_N * H_N];           // [f][h]  = w_t2[h][f]   (fp16)

__device__ __forceinline__ float b2f(u16 u) {
    union { float f; uint32_t i; } v; v.i = ((uint32_t)u) << 16; return v.f;
}
__device__ __forceinline__ float ld(const void* p, int idx, bool isbf) {
    if (isbf) return b2f(((const u16*)p)[idx]);
    return ((const float*)p)[idx];
}
__device__ __forceinline__ bool probe_bf16(const void* node_mask) {
    return ((const u16*)node_mask)[0] == 0x3F80u;   // 1.0 bf16; fp32 LE low half is 0x0000
}
// 8 consecutive elems, dtype-adaptive, vectorized
__device__ __forceinline__ void ld8f(const void* p, size_t idx, bool isbf, float* o) {
    if (isbf) {
        union { int4 v; u16 h[8]; } u;
        u.v = *(const int4*)((const u16*)p + idx);
        #pragma unroll
        for (int i = 0; i < 8; i++) o[i] = b2f(u.h[i]);
    } else {
        const float4* q = (const float4*)((const float*)p + idx);
        float4 x = q[0], y = q[1];
        o[0]=x.x; o[1]=x.y; o[2]=x.z; o[3]=x.w;
        o[4]=y.x; o[5]=y.y; o[6]=y.z; o[7]=y.w;
    }
}
__device__ __forceinline__ f16x8 ldfrag(const void* p) {
    union { int4 i; f16x8 h; } u; u.i = *(const int4*)p; return u.h;
}

// ---------------- K1: node LN + left/right projections (unchanged, proven) ----------------
__global__ void k_leftright(const void* __restrict__ node_vec, const void* __restrict__ node_mask,
                            const void* __restrict__ op_scale, const void* __restrict__ op_bias,
                            const void* __restrict__ w_left, const void* __restrict__ b_left,
                            const void* __restrict__ w_right, const void* __restrict__ b_right) {
    bool isbf = probe_bf16(node_mask);
    int a = blockIdx.x;
    int f = threadIdx.x;            // 128 threads = 2 waves
    __shared__ float sAct[F_N];
    __shared__ float sRed[4];
    float x = ld(node_vec, a * F_N + f, isbf);
    float s1 = x, s2 = x * x;
    for (int o = 1; o < 64; o <<= 1) { s1 += __shfl_xor(s1, o); s2 += __shfl_xor(s2, o); }
    int wv = threadIdx.x >> 6;
    if ((threadIdx.x & 63) == 0) { sRed[wv * 2] = s1; sRed[wv * 2 + 1] = s2; }
    __syncthreads();
    float sum = sRed[0] + sRed[2], sq = sRed[1] + sRed[3];
    float mu = sum * (1.0f / F_N);
    float var = sq * (1.0f / F_N) - mu * mu;
    float rs = rsqrtf(var + LN_EPS);
    sAct[f] = (x - mu) * rs * ld(op_scale, f, isbf) + ld(op_bias, f, isbf);
    __syncthreads();
    if (threadIdx.x < 64) {
        int c = threadIdx.x & 31;
        bool isL = threadIdx.x < 32;
        const void* W = isL ? w_left : w_right;
        const void* B = isL ? b_left : b_right;
        float acc = ld(B, c, isbf);
        for (int ff = 0; ff < F_N; ff++) acc += sAct[ff] * ld(W, ff * C_N + c, isbf);
        acc *= ld(node_mask, a, isbf);
        float* dst = isL ? g_left : g_right;
        dst[a * C_N + c] = acc;
    }
}

// ---------------- K2: M[b][f][c] = sum_d right[b,d] * w_out[(c*32+d), f] (unchanged) ----------------
__global__ void k_M(const void* __restrict__ w_out, const void* __restrict__ node_mask) {
    bool isbf = probe_bf16(node_mask);
    int b = blockIdx.x;
    int f = threadIdx.x;            // 128 threads
    __shared__ float sR[C_N];
    if (f < C_N) sR[f] = g_right[b * C_N + f];
    __syncthreads();
    for (int c = 0; c < C_N; c++) {
        float acc = 0.f;
        for (int d = 0; d < C_N; d++) acc += sR[d] * ld(w_out, (c * C_N + d) * F_N + f, isbf);
        g_M[(b * F_N + f) * C_N + c] = acc;
    }
}

// ---------------- K2b: pre-transpose MLP weights to fp16 ----------------
// gW1T[h][k] = w_t1[k][h]   (w_t1 is [F_N][H_N] row-major)
// gW2T[f][h] = w_t2[h][f]   (w_t2 is [H_N][F_N] row-major)
__global__ void k_wt(const void* __restrict__ w_t1, const void* __restrict__ w_t2,
                     const void* __restrict__ node_mask) {
    bool isbf = probe_bf16(node_mask);
    int t = blockIdx.x * 256 + threadIdx.x;     // 0..65535
    int h = t >> 7, k = t & 127;
    gW1T[t] = (f16)ld(w_t1, k * H_N + h, isbf);
    int f2 = t >> 9, h2 = t & 511;
    gW2T[t] = (f16)ld(w_t2, h2 * F_N + f2, isbf);
}

// ---------------- K3: fused edge + LN + MLP + residual ----------------
// Per block: 64 rows = 8 a's x 8 b's. E in fp32 (VALU), MLP via f16 MFMA, fp32 accum.
// LDS map (62464 B total):
//   REGION A @0     : sE fp32[64][128] rows 512B (phases 1-3)
//                     later: sW1 @0 (16KB, [64 n][128 k] f16, 256B rows)
//                            sW2 @16384 (16KB, [128 f][64 kh] f16, 128B rows)
//                            sH  @32768 ( 8KB, [64 r][64 kh] f16, 128B rows)
//   sX   @40960     : f16[64][128] rows 256B
//   consts @57344   : sB1[512] | sScale[128] | sBias[128] | sBout[128] | sB2[128] | sLeft[8][32]
// All tiles use byte ^= (row&7)<<4 XOR swizzle (write AND read sides).
#define SM_X   40960
#define SM_W2  16384
#define SM_H   32768

__global__ __launch_bounds__(256, 2) void k_fused(
    const void* __restrict__ edge_vec, const void* __restrict__ b_out,
    const void* __restrict__ tr_scale, const void* __restrict__ tr_bias,
    const void* __restrict__ b_t1, const void* __restrict__ b_t2,
    const void* __restrict__ node_mask, float* __restrict__ out)
{
    bool isbf = probe_bf16(node_mask);
    __shared__ __align__(16) unsigned char smem[62464];
    float* sB1    = (float*)(smem + 57344);
    float* sScale = (float*)(smem + 59392);
    float* sBias  = (float*)(smem + 59904);
    float* sBout  = (float*)(smem + 60416);
    float* sB2    = (float*)(smem + 60928);
    float* sLeft  = (float*)(smem + 61440);

    const int t = threadIdx.x;              // 256 threads = 4 waves
    const int lane = t & 63, wid = t >> 6;
    const int a0 = blockIdx.y * 8, b0 = blockIdx.x * 8;

    // ---- phase 0: stage consts + left tile ----
    sB1[t]       = ld(b_t1, t, isbf);
    sB1[t + 256] = ld(b_t1, t + 256, isbf);
    if (t < 128) {
        sScale[t] = ld(tr_scale, t, isbf);
        sBias[t]  = ld(tr_bias, t, isbf);
        sBout[t]  = ld(b_out, t, isbf);
        sB2[t]    = ld(b_t2, t, isbf);
    }
    {
        int ai = t >> 5, c = t & 31;
        sLeft[ai * 32 + c] = g_left[(a0 + ai) * C_N + c];
    }
    __syncthreads();

    // ---- phase 1: E[r][f] = edge_vec + sum_c left[a,c]*M[b,f,c] + b_out[f]  (fp32) ----
    {
        const int fg = t & 15, bi = (t >> 4) & 7, ag = t >> 7;   // ag uniform per wave
        const int f0 = fg * 8;
        const int b = b0 + bi;
        float acc[4][8];
        #pragma unroll
        for (int ii = 0; ii < 4; ii++) {
            int a = a0 + ag * 4 + ii;
            size_t rG = ((size_t)a * A_N + b) * F_N + f0;
            float ev[8]; ld8f(edge_vec, rG, isbf, ev);
            #pragma unroll
            for (int j = 0; j < 8; j++) acc[ii][j] = ev[j] + sBout[f0 + j];
        }
        const float4* Mv = (const float4*)(g_M + ((size_t)b * F_N + f0) * C_N); // Mv[j*8+cv]
        #pragma unroll
        for (int cv = 0; cv < 8; cv++) {
            float4 L[4];
            #pragma unroll
            for (int ii = 0; ii < 4; ii++)
                L[ii] = *(const float4*)&sLeft[(ag * 4 + ii) * 32 + cv * 4];  // LDS broadcast
            #pragma unroll
            for (int j = 0; j < 8; j++) {
                float4 m4 = Mv[j * 8 + cv];
                #pragma unroll
                for (int ii = 0; ii < 4; ii++)
                    acc[ii][j] += L[ii].x*m4.x + L[ii].y*m4.y + L[ii].z*m4.z + L[ii].w*m4.w;
            }
        }
        #pragma unroll
        for (int ii = 0; ii < 4; ii++) {
            int r = (ag * 4 + ii) * 8 + bi;
            #pragma unroll
            for (int half = 0; half < 2; half++) {
                float4 v = make_float4(acc[ii][half*4+0], acc[ii][half*4+1],
                                       acc[ii][half*4+2], acc[ii][half*4+3]);
                int byte = f0 * 4 + half * 16;
                *(float4*)(smem + r * 512 + (byte ^ ((r & 7) << 4))) = v;
            }
        }
    }
    __syncthreads();

    // ---- phase 2: LayerNorm rows of sE -> sX (f16) ----
    {
        int r = t >> 2, q = t & 3;          // 4 threads per row, 32 f each
        int fbase = q * 32;
        float e[32];
        #pragma unroll
        for (int i = 0; i < 8; i++) {
            int byte = (fbase + i * 4) * 4;
            float4 v = *(const float4*)(smem + r * 512 + (byte ^ ((r & 7) << 4)));
            e[i*4+0]=v.x; e[i*4+1]=v.y; e[i*4+2]=v.z; e[i*4+3]=v.w;
        }
        float s1 = 0.f, s2 = 0.f;
        #pragma unroll
        for (int i = 0; i < 32; i++) { s1 += e[i]; s2 += e[i] * e[i]; }
        s1 += __shfl_xor(s1, 1); s2 += __shfl_xor(s2, 1);
        s1 += __shfl_xor(s1, 2); s2 += __shfl_xor(s2, 2);
        float mu = s1 * (1.0f / F_N);
        float var = s2 * (1.0f / F_N) - mu * mu;
        float rs = rsqrtf(var + LN_EPS);
        #pragma unroll
        for (int i = 0; i < 4; i++) {
            f16 tmp[8];
            #pragma unroll
            for (int j = 0; j < 8; j++) {
                int f = fbase + i * 8 + j;
                tmp[j] = (f16)((e[i*8+j] - mu) * rs * sScale[f] + sBias[f]);
            }
            int byte = (fbase + i * 8) * 2;
            *(int4*)(smem + SM_X + r * 256 + (byte ^ ((r & 7) << 4))) = *(int4*)tmp;
        }
    }
    __syncthreads();

    // ---- phase 3: init acc2 = E + b2 (residual folded in); preload X A-fragments ----
    const int wr = wid >> 1, wc = wid & 1;   // wave grid 2x2
    f32x4 acc2[2][4];
    #pragma unroll
    for (int mr = 0; mr < 2; mr++)
        #pragma unroll
        for (int nc = 0; nc < 4; nc++)
            #pragma unroll
            for (int reg = 0; reg < 4; reg++) {
                int r = wr * 32 + mr * 16 + (lane >> 4) * 4 + reg;
                int f = wc * 64 + nc * 16 + (lane & 15);
                int byte = f * 4;
                float ev = *(const float*)(smem + r * 512 + (byte ^ ((r & 7) << 4)));
                acc2[mr][nc][reg] = ev + sB2[f];
            }
    f16x8 a1[2][4];                          // X rows in regs, reused across all chunks
    #pragma unroll
    for (int mr = 0; mr < 2; mr++)
        #pragma unroll
        for (int ks = 0; ks < 4; ks++) {
            int r = wr * 32 + mr * 16 + (lane & 15);
            int byte = ks * 64 + (lane >> 4) * 16;
            a1[mr][ks] = ldfrag(smem + SM_X + r * 256 + (byte ^ ((r & 7) << 4)));
        }
    __syncthreads();   // sE region now dead -> reused for sW1/sW2/sH

    // ---- phase 4: hidden chunks of 64 ----
    for (int ch = 0; ch < 8; ch++) {
        int h0 = ch * 64;
        // stage W1 chunk [64 n][128 k] and W2 chunk [128 f][64 kh]
        {
            int n = t >> 2, seg = t & 3;
            const int4* src = (const int4*)(gW1T + (size_t)(h0 + n) * F_N) + seg * 4;
            #pragma unroll
            for (int i = 0; i < 4; i++) {
                int byte = seg * 64 + i * 16;
                *(int4*)(smem + n * 256 + (byte ^ ((n & 7) << 4))) = src[i];
            }
            int f = t >> 1, sg2 = t & 1;
            const int4* s2 = (const int4*)(gW2T + (size_t)f * H_N + h0) + sg2 * 4;
            #pragma unroll
            for (int i = 0; i < 4; i++) {
                int byte = sg2 * 64 + i * 16;
                *(int4*)(smem + SM_W2 + f * 128 + (byte ^ ((f & 7) << 4))) = s2[i];
            }
        }
        __syncthreads();

        // GEMM1: H_chunk[64r x 64j] = X @ W1chunk ; wave tile 32x32
        f32x4 acc1[2][2];
        #pragma unroll
        for (int mr = 0; mr < 2; mr++)
            #pragma unroll
            for (int nc = 0; nc < 2; nc++)
                acc1[mr][nc] = (f32x4){0.f, 0.f, 0.f, 0.f};
        #pragma unroll
        for (int ks = 0; ks < 4; ks++) {
            f16x8 bfr[2];
            #pragma unroll
            for (int nc = 0; nc < 2; nc++) {
                int n = wc * 32 + nc * 16 + (lane & 15);
                int byte = ks * 64 + (lane >> 4) * 16;
                bfr[nc] = ldfrag(smem + n * 256 + (byte ^ ((n & 7) << 4)));
            }
            #pragma unroll
            for (int mr = 0; mr < 2; mr++)
                #pragma unroll
                for (int nc = 0; nc < 2; nc++)
                    acc1[mr][nc] = __builtin_amdgcn_mfma_f32_16x16x32_f16(
                        a1[mr][ks], bfr[nc], acc1[mr][nc], 0, 0, 0);
        }
        // bias + relu + store H (f16)
        #pragma unroll
        for (int mr = 0; mr < 2; mr++)
            #pragma unroll
            for (int nc = 0; nc < 2; nc++) {
                int jl = wc * 32 + nc * 16 + (lane & 15);
                float b1v = sB1[h0 + jl];
                #pragma unroll
                for (int reg = 0; reg < 4; reg++) {
                    int r = wr * 32 + mr * 16 + (lane >> 4) * 4 + reg;
                    float h = fmaxf(acc1[mr][nc][reg] + b1v, 0.f);
                    int byte = jl * 2;
                    *(f16*)(smem + SM_H + r * 128 + (byte ^ ((r & 7) << 4))) = (f16)h;
                }
            }
        __syncthreads();

        // GEMM2: acc2 += H_chunk @ W2chunk ; wave tile 32r x 64f
        #pragma unroll
        for (int ks = 0; ks < 2; ks++) {
            f16x8 afr[2], bfr2[4];
            #pragma unroll
            for (int mr = 0; mr < 2; mr++) {
                int r = wr * 32 + mr * 16 + (lane & 15);
                int byte = ks * 64 + (lane >> 4) * 16;
                afr[mr] = ldfrag(smem + SM_H + r * 128 + (byte ^ ((r & 7) << 4)));
            }
            #pragma unroll
            for (int nc = 0; nc < 4; nc++) {
                int f = wc * 64 + nc * 16 + (lane & 15);
                int byte = ks * 64 + (lane >> 4) * 16;
                bfr2[nc] = ldfrag(smem + SM_W2 + f * 128 + (byte ^ ((f & 7) << 4)));
            }
            #pragma unroll
            for (int mr = 0; mr < 2; mr++)
                #pragma unroll
                for (int nc = 0; nc < 4; nc++)
                    acc2[mr][nc] = __builtin_amdgcn_mfma_f32_16x16x32_f16(
                        afr[mr], bfr2[nc], acc2[mr][nc], 0, 0, 0);
        }
        __syncthreads();
    }

    // ---- epilogue: out[a,b,f] = acc2 (already contains E + b2 + MLP) ----
    #pragma unroll
    for (int mr = 0; mr < 2; mr++)
        #pragma unroll
        for (int nc = 0; nc < 4; nc++)
            #pragma unroll
            for (int reg = 0; reg < 4; reg++) {
                int r = wr * 32 + mr * 16 + (lane >> 4) * 4 + reg;
                int f = wc * 64 + nc * 16 + (lane & 15);
                int a = a0 + (r >> 3), b = b0 + (r & 7);
                out[((size_t)a * A_N + b) * F_N + f] = acc2[mr][nc][reg];
            }
}

extern "C" void kernel_launch(void* const* d_in, const int* in_sizes, int n_in,
                              void* d_out, int out_size, void* d_ws, size_t ws_size,
                              hipStream_t stream) {
    const void* node_vec  = d_in[0];
    const void* edge_vec  = d_in[1];
    const void* node_mask = d_in[2];
    // d_in[3] edge_mask: unused by reference
    const void* op_scale  = d_in[4];
    const void* op_bias   = d_in[5];
    const void* w_left    = d_in[6];
    const void* b_left    = d_in[7];
    const void* w_right   = d_in[8];
    const void* b_right   = d_in[9];
    const void* w_out     = d_in[10];
    const void* b_out     = d_in[11];
    const void* tr_scale  = d_in[12];
    const void* tr_bias   = d_in[13];
    const void* w_t1      = d_in[14];
    const void* b_t1      = d_in[15];
    const void* w_t2      = d_in[16];
    const void* b_t2      = d_in[17];
    float* out = (float*)d_out;
    (void)d_ws; (void)ws_size; (void)in_sizes; (void)n_in; (void)out_size;

    hipLaunchKernelGGL(k_leftright, dim3(A_N), dim3(128), 0, stream,
                       node_vec, node_mask, op_scale, op_bias,
                       w_left, b_left, w_right, b_right);
    hipLaunchKernelGGL(k_M, dim3(A_N), dim3(128), 0, stream, w_out, node_mask);
    hipLaunchKernelGGL(k_wt, dim3(256), dim3(256), 0, stream, w_t1, w_t2, node_mask);
    hipLaunchKernelGGL(k_fused, dim3(A_N / 8, A_N / 8), dim3(256), 0, stream,
                       edge_vec, b_out, tr_scale, tr_bias, b_t1, b_t2, node_mask, out);
}